// Round 7
// baseline (3376.794 us; speedup 1.0000x reference)
//
#include <hip/hip_runtime.h>
#include <stdint.h>

#define T_DIM 512
#define B_DIM 256
#define OBS_DIM 128
#define H_DIM 256
#define A_DIM 32
#define TB (T_DIM*B_DIM)   // 131072

typedef unsigned short u16;
typedef unsigned int   u32;
typedef _Float16 half2v __attribute__((ext_vector_type(2)));
typedef __attribute__((ext_vector_type(8))) short short8;   // 8 bf16 (4 VGPRs)
typedef __attribute__((ext_vector_type(4))) float f32x4;
typedef __attribute__((ext_vector_type(4))) u32   u32x4;

__device__ __forceinline__ float bf2f(u16 v){ return __uint_as_float(((u32)v)<<16); }
__device__ __forceinline__ u16 f2bf(float f){
    u32 x = __float_as_uint(f);
    u32 r = x + 0x7fffu + ((x>>16)&1u);   // round-to-nearest-even
    return (u16)(r>>16);
}
__device__ __forceinline__ float2 bfpair(u32 u){
    return make_float2(__uint_as_float(u<<16), __uint_as_float(u & 0xffff0000u));
}

// packed-f16-pair dot: acc += a.lo*b.lo + a.hi*b.hi
__device__ __forceinline__ float dot2(u32 a, u32 b, float c){
#if __has_builtin(__builtin_amdgcn_fdot2)
    return __builtin_amdgcn_fdot2(__builtin_bit_cast(half2v,a),
                                  __builtin_bit_cast(half2v,b), c, false);
#else
    half2v ha = __builtin_bit_cast(half2v,a), hb = __builtin_bit_cast(half2v,b);
    return fmaf((float)ha[0],(float)hb[0], fmaf((float)ha[1],(float)hb[1], c));
#endif
}

// ---------------------------------------------------------------------------
// dones dtype probe (u8 bool vs i32 vs f32) via nonzero byte positions mod 4.
// ---------------------------------------------------------------------------
__global__ void zero_flags_kernel(int* p){ if(threadIdx.x<4) p[threadIdx.x]=0; }

__global__ void detect_kernel(const unsigned char* __restrict__ d, int n, int* __restrict__ flags){
    int f=0;
    for(int p = blockIdx.x*blockDim.x+threadIdx.x; p<n; p += gridDim.x*blockDim.x){
        if(d[p]){ int m=p&3; if(m==1) f|=1; else if(m>=2) f|=2; }
    }
    if(f) atomicOr(flags, f);
}

// ---------------------------------------------------------------------------
// Recurrent weights -> packed f16 pairs: dst[((m*32+q)*256 + j)*4 + e] packs
// k=2*(4q+e), 2*(4q+e)+1 of column j of matrix m (q covers k=8q..8q+7).
// ---------------------------------------------------------------------------
__global__ void cvt_wt_kernel(const float* __restrict__ Whr, const float* __restrict__ Whz,
                              const float* __restrict__ Whn, u32* __restrict__ dst){
    int i = blockIdx.x*blockDim.x + threadIdx.x;
    if(i >= 3*32*256*4) return;
    int e = i & 3;
    int j = (i >> 2) & 255;
    int q = (i >> 10) & 31;
    int m = i >> 15;
    const float* W = (m==0) ? Whr : (m==1) ? Whz : Whn;
    int kp = q*4 + e, k = 2*kp;
    _Float16 lo = (_Float16)W[(size_t)k    *H_DIM + j];
    _Float16 hi = (_Float16)W[(size_t)(k+1)*H_DIM + j];
    dst[i] = (u32)__builtin_bit_cast(u16,lo) | ((u32)__builtin_bit_cast(u16,hi) << 16);
}

// GEMM weight f32 [K][N] -> bf16 transposed [N][K]
__global__ void cvt_wT_kernel(const float* __restrict__ W, u16* __restrict__ dst,
                              int K, int N){
    int i = blockIdx.x*blockDim.x + threadIdx.x;
    if(i >= K*N) return;
    int n = i / K;
    int k = i - n*K;
    dst[i] = f2bf(W[(size_t)k*N + n]);
}

// ---------------------------------------------------------------------------
// f32 GEMM (emb only): C[M,N](bf16) = relu(A_f32[M,K] @ W[K,N] + bias)
// ---------------------------------------------------------------------------
__global__ __launch_bounds__(256)
void gemm_f32_kernel(const float* __restrict__ A, const float* __restrict__ W,
                     const float* __restrict__ bias, u16* __restrict__ C,
                     int M, int N, int K)
{
    __shared__ float As[16][128];
    __shared__ float Ws[16][128];
    const int tid = threadIdx.x;
    const int tr = tid>>4, tc = tid&15;
    const int lar = tid>>1, lac = (tid&1)*8;
    const int lwr = tid>>4, lwc = (tid&15)*8;
    const int rowBase = blockIdx.y*128;
    const int colBase = blockIdx.x*128;

    float acc[8][8];
    #pragma unroll
    for(int i=0;i<8;i++){
        #pragma unroll
        for(int j=0;j<8;j++) acc[i][j]=0.f;
    }

    for(int kb=0; kb<K; kb+=16){
        {
            const float4* p = (const float4*)(A + (size_t)(rowBase+lar)*K + kb + lac);
            float4 a0=p[0], a1=p[1];
            As[lac+0][lar]=a0.x; As[lac+1][lar]=a0.y; As[lac+2][lar]=a0.z; As[lac+3][lar]=a0.w;
            As[lac+4][lar]=a1.x; As[lac+5][lar]=a1.y; As[lac+6][lar]=a1.z; As[lac+7][lar]=a1.w;
        }
        {
            const float4* p = (const float4*)(W + (size_t)(kb+lwr)*N + colBase + lwc);
            float4 w0 = p[0], w1 = p[1];
            *(float4*)&Ws[lwr][lwc]   = w0;
            *(float4*)&Ws[lwr][lwc+4] = w1;
        }
        __syncthreads();
        #pragma unroll
        for(int kk=0;kk<16;kk++){
            float4 a0 = *(const float4*)&As[kk][tr*8];
            float4 a1 = *(const float4*)&As[kk][tr*8+4];
            float4 w0 = *(const float4*)&Ws[kk][tc*8];
            float4 w1 = *(const float4*)&Ws[kk][tc*8+4];
            float av[8]={a0.x,a0.y,a0.z,a0.w,a1.x,a1.y,a1.z,a1.w};
            float wv[8]={w0.x,w0.y,w0.z,w0.w,w1.x,w1.y,w1.z,w1.w};
            #pragma unroll
            for(int i=0;i<8;i++){
                #pragma unroll
                for(int j=0;j<8;j++) acc[i][j] = fmaf(av[i], wv[j], acc[i][j]);
            }
        }
        __syncthreads();
    }

    float bv[8];
    #pragma unroll
    for(int j=0;j<8;j++) bv[j] = bias[colBase + tc*8 + j];
    #pragma unroll
    for(int i=0;i<8;i++){
        u16 h[8];
        #pragma unroll
        for(int j=0;j<8;j++){
            float v = fmaxf(acc[i][j] + bv[j], 0.f);
            h[j] = f2bf(v);
        }
        *(uint4*)(C + (size_t)(rowBase + tr*8 + i)*N + colBase + tc*8) = *(uint4*)h;
    }
}

// ---------------------------------------------------------------------------
// MFMA bf16 GEMM: C[M,N](bf16) = opt_relu(A_bf16[M,K] @ Bt^T + bias), Bt bf16
// [N][K]. 128x128 tile, BK=32, 4 waves 2x2, 16x mfma_f32_16x16x32_bf16 each.
// ---------------------------------------------------------------------------
template<int RELU>
__global__ __launch_bounds__(256, 2)
void gemm_mfma_kernel(const u16* __restrict__ A, const u16* __restrict__ Bt,
                      const float* __restrict__ bias, u16* __restrict__ C,
                      int M, int N, int K)
{
    __shared__ u16 As[128*32];
    __shared__ u16 Bs[128*32];
    const int tid  = threadIdx.x;
    const int wave = tid >> 6;
    const int lane = tid & 63;
    const int ln15 = lane & 15;
    const int quad = lane >> 4;
    const int wm = wave & 1, wn = wave >> 1;
    const int rowBase = blockIdx.y*128;
    const int colBase = blockIdx.x*128;

    f32x4 acc[4][4] = {};

    const int sr = tid >> 1;
    const int sc = (tid & 1) * 16;

    for(int kb = 0; kb < K; kb += 32){
        const u16* ag = A  + (size_t)(rowBase+sr)*K + kb + sc;
        const u16* bg = Bt + (size_t)(colBase+sr)*K + kb + sc;
        uint4 av0 = *(const uint4*)ag;
        uint4 av1 = *(const uint4*)(ag+8);
        uint4 bv0 = *(const uint4*)bg;
        uint4 bv1 = *(const uint4*)(bg+8);
        *(uint4*)&As[sr*32 + sc]     = av0;
        *(uint4*)&As[sr*32 + sc + 8] = av1;
        *(uint4*)&Bs[sr*32 + sc]     = bv0;
        *(uint4*)&Bs[sr*32 + sc + 8] = bv1;
        __syncthreads();

        short8 af[4], bf[4];
        #pragma unroll
        for(int mt=0;mt<4;mt++)
            af[mt] = *(const short8*)&As[(wm*64+mt*16+ln15)*32 + quad*8];
        #pragma unroll
        for(int nt=0;nt<4;nt++)
            bf[nt] = *(const short8*)&Bs[(wn*64+nt*16+ln15)*32 + quad*8];
        #pragma unroll
        for(int mt=0;mt<4;mt++){
            #pragma unroll
            for(int nt=0;nt<4;nt++){
                acc[mt][nt] = __builtin_amdgcn_mfma_f32_16x16x32_bf16(
                                  af[mt], bf[nt], acc[mt][nt], 0, 0, 0);
            }
        }
        __syncthreads();
    }

    #pragma unroll
    for(int nt=0;nt<4;nt++){
        int n = colBase + wn*64 + nt*16 + ln15;
        float bv = bias[n];
        #pragma unroll
        for(int mt=0;mt<4;mt++){
            #pragma unroll
            for(int r=0;r<4;r++){
                int m = rowBase + wm*64 + mt*16 + quad*4 + r;
                float v = acc[mt][nt][r] + bv;
                if(RELU) v = fmaxf(v, 0.f);
                C[(size_t)m*N + n] = f2bf(v);
            }
        }
    }
}

// ---------------------------------------------------------------------------
// GRU scan: 256 blocks (one batch row) x 512 threads. Thread (p=tid>>8, j):
//   p=0: full Whr col j (32 u32x4) + Whn col j, k in [0,128)   (16 u32x4)
//   p=1: full Whz col j (32 u32x4) + Whn col j, k in [128,256) (16 u32x4)
// = 192 weight VGPRs/thread, plain loads, fully-static unrolled indexing.
// __launch_bounds__(512,2) -> 256-VGPR cap; need ~230 -> resident, no remat.
// h packed f16 in LDS, broadcast b128 reads. p=1 ships (iz+z_acc) and its
// n-partial through LDS; p=0 computes gates. 2 barriers/step.
// ---------------------------------------------------------------------------
__global__ __launch_bounds__(512, 2)
void scan_kernel(const u16* __restrict__ gi, const void* __restrict__ dones,
                 const int* __restrict__ flags, const u32x4* __restrict__ Wt4,
                 const float* __restrict__ bhn, float* __restrict__ h_carry,
                 u16* __restrict__ y, int t0, int Tc)
{
    __shared__ __align__(16) u32 hbuf[2][128];   // 256 packed f16 each
    __shared__ float zpre[256];                  // iz + z_acc  (from p=1)
    __shared__ float n1b[256];                   // n-partial k>=128 (from p=1)
    const int tid = threadIdx.x;
    const int j   = tid & 255;
    const int p   = tid >> 8;
    const int row = blockIdx.x;
    const int fl  = flags[0];
    const int mode = (fl&1) ? 0 : ((fl&2) ? 2 : 1);  // 0=u8, 1=i32, 2=f32

    auto getdone = [&](int t)->bool{
        int idx = t*B_DIM + row;
        if(mode==0) return ((const unsigned char*)dones)[idx] != 0;
        if(mode==1) return ((const int*)dones)[idx] != 0;
        return ((const float*)dones)[idx] != 0.f;
    };

    // ---- one-time register-resident weight load (plain, statically unrolled)
    const u32x4* baseA = Wt4 + (size_t)(p*32)*256 + j;          // m=0 or 1
    const u32x4* baseN = Wt4 + (size_t)(64 + p*16)*256 + j;     // m=2 halves
    u32x4 wA[32], wN[16];
    #pragma unroll
    for(int q=0;q<32;q++) wA[q] = baseA[q*256];
    #pragma unroll
    for(int q=0;q<16;q++) wN[q] = baseN[q*256];

    const float bh = bhn[j];
    float hoj = 0.f;
    if(p == 0){
        bool d0 = getdone(t0);
        hoj = d0 ? 0.f : h_carry[(size_t)row*H_DIM + j];
        ((_Float16*)hbuf[0])[j] = (_Float16)hoj;
    }
    __syncthreads();

    int cur = 0;
    for(int t=0; t<Tc; ++t){
        // gate-input loads up front (latency hides under the dot phase)
        size_t gbase = ((size_t)t*B_DIM + row)*768;
        float gv0 = bf2f(gi[gbase + p*256 + j]);          // p=0: ir, p=1: iz
        float inn = 0.f; bool dn = false;
        if(p == 0){
            inn = bf2f(gi[gbase + 512 + j]);
            dn  = (t < Tc-1) ? getdone(t0+t+1) : false;
        }

        // dot: full matrix (r or z) over all k
        float a0=0.f, a1=0.f;
        const u32x4* hb = (const u32x4*)hbuf[cur];
        #pragma unroll
        for(int q=0;q<32;q++){
            u32x4 hv = hb[q];
            u32x4 wq = wA[q];
            a0 = dot2(wq[0], hv[0], a0);
            a1 = dot2(wq[1], hv[1], a1);
            a0 = dot2(wq[2], hv[2], a0);
            a1 = dot2(wq[3], hv[3], a1);
        }
        // n half: p=0 uses h[k<128] (q 0..15), p=1 uses h[k>=128] (q 16..31)
        float n0=0.f, n1=0.f;
        #pragma unroll
        for(int q=0;q<16;q++){
            u32x4 hv = hb[p*16 + q];
            u32x4 wq = wN[q];
            n0 = dot2(wq[0], hv[0], n0);
            n1 = dot2(wq[1], hv[1], n1);
            n0 = dot2(wq[2], hv[2], n0);
            n1 = dot2(wq[3], hv[3], n1);
        }
        if(p == 1){
            zpre[j] = gv0 + a0 + a1;   // iz + z_acc
            n1b[j]  = n0 + n1;
        }
        __syncthreads();

        if(p == 0){
            float r = 1.f/(1.f + __expf(-(gv0 + a0 + a1)));
            float z = 1.f/(1.f + __expf(-zpre[j]));
            float x = inn + r*(n0 + n1 + n1b[j] + bh);
            float e2 = __expf(2.f*x);
            float n = 1.f - 2.f/(e2 + 1.f);          // tanh(x)
            float hn = (1.f - z)*n + z*hoj;
            y[((size_t)t*B_DIM + row)*H_DIM + j] = f2bf(hn);
            hoj = dn ? 0.f : hn;                     // dn=false on last chunk step
            ((_Float16*)hbuf[cur^1])[j] = (_Float16)hoj;
        }
        __syncthreads();
        cur ^= 1;
    }

    if(p == 0) h_carry[(size_t)row*H_DIM + j] = hoj;  // raw carry
}

// ---------------------------------------------------------------------------
// Actor head stage 2: logits[rows,32] = ah[rows,256] @ W_a2 + b_a2 - (1-avail)*1e10
// ---------------------------------------------------------------------------
__global__ __launch_bounds__(256)
void actor2_kernel(const u16* __restrict__ ah, const float* __restrict__ W_a2,
                   const float* __restrict__ b_a2, const float* __restrict__ avail,
                   float* __restrict__ logits)
{
    __shared__ u16 ahs[64][264];
    const int tid = threadIdx.x;
    const int r0 = blockIdx.x*64;
    {
        int row = tid & 63;
        int c0 = (tid >> 6) * 64;
        const uint4* gp = (const uint4*)(ah + (size_t)(r0+row)*H_DIM + c0);
        #pragma unroll
        for(int q=0;q<8;q++){
            uint4 u = gp[q];
            u32* dst = (u32*)&ahs[row][c0 + q*8];
            dst[0]=u.x; dst[1]=u.y; dst[2]=u.z; dst[3]=u.w;
        }
    }
    __syncthreads();
    const int c  = tid & 31;
    const int rg = tid >> 5;   // 0..7
    float acc[8]={0.f,0.f,0.f,0.f,0.f,0.f,0.f,0.f};
    float bc = b_a2[c];
    for(int k=0;k<H_DIM;k+=4){
        float w0 = W_a2[(k+0)*A_DIM + c];
        float w1 = W_a2[(k+1)*A_DIM + c];
        float w2 = W_a2[(k+2)*A_DIM + c];
        float w3 = W_a2[(k+3)*A_DIM + c];
        #pragma unroll
        for(int rr=0;rr<8;rr++){
            uint2 av = *(const uint2*)&ahs[rg*8+rr][k];
            float2 p0 = bfpair(av.x), p1 = bfpair(av.y);
            acc[rr] = fmaf(p0.x,w0,fmaf(p0.y,w1,fmaf(p1.x,w2,fmaf(p1.y,w3,acc[rr]))));
        }
    }
    #pragma unroll
    for(int rr=0;rr<8;rr++){
        int grow = r0 + rg*8 + rr;
        float av = avail[(size_t)grow*A_DIM + c];
        logits[(size_t)grow*A_DIM + c] = acc[rr] + bc - (1.f-av)*1e10f;
    }
}

// ---------------------------------------------------------------------------
// Critic head stage 2: value[row] = ch[row,256] @ W_c2 + b_c2. Wave per row.
// ---------------------------------------------------------------------------
__global__ __launch_bounds__(256)
void critic2_kernel(const u16* __restrict__ ch, const float* __restrict__ W_c2,
                    const float* __restrict__ b_c2, float* __restrict__ value)
{
    const int lane = threadIdx.x & 63;
    const int wid  = threadIdx.x >> 6;
    const int row  = blockIdx.x*4 + wid;
    uint2 av = *(const uint2*)(ch + (size_t)row*H_DIM + lane*4);
    float2 p0 = bfpair(av.x), p1 = bfpair(av.y);
    float4 wv = *(const float4*)(W_c2 + lane*4);
    float acc = p0.x*wv.x + p0.y*wv.y + p1.x*wv.z + p1.y*wv.w;
    #pragma unroll
    for(int off=32; off>0; off>>=1) acc += __shfl_down(acc, off, 64);
    if(lane==0) value[row] = acc + b_c2[0];
}

// ---------------------------------------------------------------------------
extern "C" void kernel_launch(void* const* d_in, const int* in_sizes, int n_in,
                              void* d_out, int out_size, void* d_ws, size_t ws_size,
                              hipStream_t stream)
{
    const float* hidden = (const float*)d_in[0];
    const float* obs    = (const float*)d_in[1];
    const void*  dones  = d_in[2];
    const float* avail  = (const float*)d_in[3];
    const float* W_emb  = (const float*)d_in[4];
    const float* b_emb  = (const float*)d_in[5];
    const float* Wi     = (const float*)d_in[6];
    const float* bi     = (const float*)d_in[7];
    const float* Whr    = (const float*)d_in[8];
    const float* Whz    = (const float*)d_in[9];
    const float* Whn    = (const float*)d_in[10];
    const float* bhn    = (const float*)d_in[11];
    const float* W_a1   = (const float*)d_in[12];
    const float* b_a1   = (const float*)d_in[13];
    const float* W_a2   = (const float*)d_in[14];
    const float* b_a2   = (const float*)d_in[15];
    const float* W_c1   = (const float*)d_in[16];
    const float* b_c1   = (const float*)d_in[17];
    const float* W_c2   = (const float*)d_in[18];
    const float* b_c2   = (const float*)d_in[19];

    float* out_hidden = (float*)d_out;                       // 65536
    float* out_logits = out_hidden + (size_t)B_DIM*H_DIM;    // 4194304
    float* out_value  = out_logits + (size_t)TB*A_DIM;       // 131072

    // ---- workspace layout (chunk size adapted to ws_size, deterministic) ----
    const size_t fixed = 393216 + 393216 + 131072 + 131072 + 262144 + 256;
    int Tc = 4;
    for(int cand = 64; cand >= 4; cand >>= 1){
        size_t need = fixed + (size_t)cand*(393216 /*gi*/ + 2*131072 /*emb, y*/);
        if(need <= ws_size){ Tc = cand; break; }
    }
    const int NC = T_DIM / Tc;

    uint8_t* ws = (uint8_t*)d_ws;
    size_t off = 0;
    u32*  wt_b    = (u32*)(ws + off); off += 393216;   // scan weights, packed f16
    u16*  wiT     = (u16*)(ws + off); off += 393216;   // Wi^T bf16 [768][256]
    u16*  wa1T    = (u16*)(ws + off); off += 131072;   // W_a1^T bf16 [256][256]
    u16*  wc1T    = (u16*)(ws + off); off += 131072;   // W_c1^T bf16 [256][256]
    float* h_carry= (float*)(ws + off); off += 262144;
    int*  flags   = (int*)(ws + off); off += 256;
    u16*  gi_c    = (u16*)(ws + off); off += (size_t)Tc*393216;
    u16*  emb_c   = (u16*)(ws + off); off += (size_t)Tc*131072;  // also ah_c, ch_c
    u16*  y_c     = (u16*)(ws + off); off += (size_t)Tc*131072;
    u16*  ah_c    = emb_c;
    u16*  ch_c    = emb_c;

    zero_flags_kernel<<<1, 64, 0, stream>>>(flags);
    detect_kernel<<<64, 256, 0, stream>>>((const unsigned char*)dones, TB, flags);
    cvt_wt_kernel<<<384, 256, 0, stream>>>(Whr, Whz, Whn, wt_b);
    cvt_wT_kernel<<<768, 256, 0, stream>>>(Wi,   wiT,  256, 768);
    cvt_wT_kernel<<<256, 256, 0, stream>>>(W_a1, wa1T, 256, 256);
    cvt_wT_kernel<<<256, 256, 0, stream>>>(W_c1, wc1T, 256, 256);
    hipMemcpyAsync(h_carry, hidden, (size_t)B_DIM*H_DIM*sizeof(float),
                   hipMemcpyDeviceToDevice, stream);

    const int Mc = Tc*B_DIM;
    const int gy = Mc/128;

    for(int c = 0; c < NC; ++c){
        const int t0 = c*Tc;
        const float* obs_c = obs + (size_t)t0*B_DIM*OBS_DIM;
        // emb = relu(obs @ W_emb + b_emb)  (f32 A)
        gemm_f32_kernel<<<dim3(2,gy), 256, 0, stream>>>(obs_c, W_emb, b_emb, emb_c, Mc, 256, 128);
        // gi = emb @ Wi + bi  (MFMA)
        gemm_mfma_kernel<0><<<dim3(6,gy), 256, 0, stream>>>(emb_c, wiT, bi, gi_c, Mc, 768, 256);
        // GRU scan chunk: 256 blocks (one per batch row) x 512 threads
        scan_kernel<<<256, 512, 0, stream>>>(gi_c, dones, flags, (const u32x4*)wt_b,
                                             bhn, h_carry, y_c, t0, Tc);
        // actor head
        gemm_mfma_kernel<1><<<dim3(2,gy), 256, 0, stream>>>(y_c, wa1T, b_a1, ah_c, Mc, 256, 256);
        actor2_kernel<<<Mc/64, 256, 0, stream>>>(ah_c, W_a2, b_a2,
                                                 avail + (size_t)t0*B_DIM*A_DIM,
                                                 out_logits + (size_t)t0*B_DIM*A_DIM);
        // critic head
        gemm_mfma_kernel<1><<<dim3(2,gy), 256, 0, stream>>>(y_c, wc1T, b_c1, ch_c, Mc, 256, 256);
        critic2_kernel<<<Mc/4, 256, 0, stream>>>(ch_c, W_c2, b_c2, out_value + (size_t)t0*B_DIM);
    }

    hipMemcpyAsync(out_hidden, h_carry, (size_t)B_DIM*H_DIM*sizeof(float),
                   hipMemcpyDeviceToDevice, stream);
}

// Round 8
// 1741.803 us; speedup vs baseline: 1.9387x; 1.9387x over previous
//
#include <hip/hip_runtime.h>
#include <stdint.h>

#define T_DIM 512
#define B_DIM 256
#define OBS_DIM 128
#define H_DIM 256
#define A_DIM 32
#define TB (T_DIM*B_DIM)   // 131072

typedef unsigned short u16;
typedef unsigned int   u32;
typedef _Float16 half2v __attribute__((ext_vector_type(2)));
typedef __attribute__((ext_vector_type(8))) short short8;   // 8 bf16 (4 VGPRs)
typedef __attribute__((ext_vector_type(4))) float f32x4;
typedef __attribute__((ext_vector_type(4))) u32   u32x4;

__device__ __forceinline__ float bf2f(u16 v){ return __uint_as_float(((u32)v)<<16); }
__device__ __forceinline__ u16 f2bf(float f){
    u32 x = __float_as_uint(f);
    u32 r = x + 0x7fffu + ((x>>16)&1u);   // round-to-nearest-even
    return (u16)(r>>16);
}
__device__ __forceinline__ float2 bfpair(u32 u){
    return make_float2(__uint_as_float(u<<16), __uint_as_float(u & 0xffff0000u));
}

// packed-f16-pair dot: acc += a.lo*b.lo + a.hi*b.hi
__device__ __forceinline__ float dot2(u32 a, u32 b, float c){
#if __has_builtin(__builtin_amdgcn_fdot2)
    return __builtin_amdgcn_fdot2(__builtin_bit_cast(half2v,a),
                                  __builtin_bit_cast(half2v,b), c, false);
#else
    half2v ha = __builtin_bit_cast(half2v,a), hb = __builtin_bit_cast(half2v,b);
    return fmaf((float)ha[0],(float)hb[0], fmaf((float)ha[1],(float)hb[1], c));
#endif
}

// ---------------------------------------------------------------------------
// dones dtype probe (u8 bool vs i32 vs f32) via nonzero byte positions mod 4.
// ---------------------------------------------------------------------------
__global__ void zero_flags_kernel(int* p){ if(threadIdx.x<4) p[threadIdx.x]=0; }

__global__ void detect_kernel(const unsigned char* __restrict__ d, int n, int* __restrict__ flags){
    int f=0;
    for(int p = blockIdx.x*blockDim.x+threadIdx.x; p<n; p += gridDim.x*blockDim.x){
        if(d[p]){ int m=p&3; if(m==1) f|=1; else if(m>=2) f|=2; }
    }
    if(f) atomicOr(flags, f);
}

// ---------------------------------------------------------------------------
// Recurrent weights -> packed f16 pairs: dst[((m*32+q)*256 + j)*4 + e] packs
// k=2*(4q+e), 2*(4q+e)+1 of column j of matrix m (q covers k=8q..8q+7).
// ---------------------------------------------------------------------------
__global__ void cvt_wt_kernel(const float* __restrict__ Whr, const float* __restrict__ Whz,
                              const float* __restrict__ Whn, u32* __restrict__ dst){
    int i = blockIdx.x*blockDim.x + threadIdx.x;
    if(i >= 3*32*256*4) return;
    int e = i & 3;
    int j = (i >> 2) & 255;
    int q = (i >> 10) & 31;
    int m = i >> 15;
    const float* W = (m==0) ? Whr : (m==1) ? Whz : Whn;
    int kp = q*4 + e, k = 2*kp;
    _Float16 lo = (_Float16)W[(size_t)k    *H_DIM + j];
    _Float16 hi = (_Float16)W[(size_t)(k+1)*H_DIM + j];
    dst[i] = (u32)__builtin_bit_cast(u16,lo) | ((u32)__builtin_bit_cast(u16,hi) << 16);
}

// GEMM weight f32 [K][N] -> bf16 transposed [N][K]
__global__ void cvt_wT_kernel(const float* __restrict__ W, u16* __restrict__ dst,
                              int K, int N){
    int i = blockIdx.x*blockDim.x + threadIdx.x;
    if(i >= K*N) return;
    int n = i / K;
    int k = i - n*K;
    dst[i] = f2bf(W[(size_t)k*N + n]);
}

// ---------------------------------------------------------------------------
// f32 GEMM (emb only): C[M,N](bf16) = relu(A_f32[M,K] @ W[K,N] + bias)
// ---------------------------------------------------------------------------
__global__ __launch_bounds__(256)
void gemm_f32_kernel(const float* __restrict__ A, const float* __restrict__ W,
                     const float* __restrict__ bias, u16* __restrict__ C,
                     int M, int N, int K)
{
    __shared__ float As[16][128];
    __shared__ float Ws[16][128];
    const int tid = threadIdx.x;
    const int tr = tid>>4, tc = tid&15;
    const int lar = tid>>1, lac = (tid&1)*8;
    const int lwr = tid>>4, lwc = (tid&15)*8;
    const int rowBase = blockIdx.y*128;
    const int colBase = blockIdx.x*128;

    float acc[8][8];
    #pragma unroll
    for(int i=0;i<8;i++){
        #pragma unroll
        for(int j=0;j<8;j++) acc[i][j]=0.f;
    }

    for(int kb=0; kb<K; kb+=16){
        {
            const float4* p = (const float4*)(A + (size_t)(rowBase+lar)*K + kb + lac);
            float4 a0=p[0], a1=p[1];
            As[lac+0][lar]=a0.x; As[lac+1][lar]=a0.y; As[lac+2][lar]=a0.z; As[lac+3][lar]=a0.w;
            As[lac+4][lar]=a1.x; As[lac+5][lar]=a1.y; As[lac+6][lar]=a1.z; As[lac+7][lar]=a1.w;
        }
        {
            const float4* p = (const float4*)(W + (size_t)(kb+lwr)*N + colBase + lwc);
            float4 w0 = p[0], w1 = p[1];
            *(float4*)&Ws[lwr][lwc]   = w0;
            *(float4*)&Ws[lwr][lwc+4] = w1;
        }
        __syncthreads();
        #pragma unroll
        for(int kk=0;kk<16;kk++){
            float4 a0 = *(const float4*)&As[kk][tr*8];
            float4 a1 = *(const float4*)&As[kk][tr*8+4];
            float4 w0 = *(const float4*)&Ws[kk][tc*8];
            float4 w1 = *(const float4*)&Ws[kk][tc*8+4];
            float av[8]={a0.x,a0.y,a0.z,a0.w,a1.x,a1.y,a1.z,a1.w};
            float wv[8]={w0.x,w0.y,w0.z,w0.w,w1.x,w1.y,w1.z,w1.w};
            #pragma unroll
            for(int i=0;i<8;i++){
                #pragma unroll
                for(int j=0;j<8;j++) acc[i][j] = fmaf(av[i], wv[j], acc[i][j]);
            }
        }
        __syncthreads();
    }

    float bv[8];
    #pragma unroll
    for(int j=0;j<8;j++) bv[j] = bias[colBase + tc*8 + j];
    #pragma unroll
    for(int i=0;i<8;i++){
        u16 h[8];
        #pragma unroll
        for(int j=0;j<8;j++){
            float v = fmaxf(acc[i][j] + bv[j], 0.f);
            h[j] = f2bf(v);
        }
        *(uint4*)(C + (size_t)(rowBase + tr*8 + i)*N + colBase + tc*8) = *(uint4*)h;
    }
}

// ---------------------------------------------------------------------------
// MFMA bf16 GEMM: C[M,N](bf16) = opt_relu(A_bf16[M,K] @ Bt^T + bias), Bt bf16
// [N][K]. 128x128 tile, BK=32, 4 waves 2x2, 16x mfma_f32_16x16x32_bf16 each.
// ---------------------------------------------------------------------------
template<int RELU>
__global__ __launch_bounds__(256, 2)
void gemm_mfma_kernel(const u16* __restrict__ A, const u16* __restrict__ Bt,
                      const float* __restrict__ bias, u16* __restrict__ C,
                      int M, int N, int K)
{
    __shared__ u16 As[128*32];
    __shared__ u16 Bs[128*32];
    const int tid  = threadIdx.x;
    const int wave = tid >> 6;
    const int lane = tid & 63;
    const int ln15 = lane & 15;
    const int quad = lane >> 4;
    const int wm = wave & 1, wn = wave >> 1;
    const int rowBase = blockIdx.y*128;
    const int colBase = blockIdx.x*128;

    f32x4 acc[4][4] = {};

    const int sr = tid >> 1;
    const int sc = (tid & 1) * 16;

    for(int kb = 0; kb < K; kb += 32){
        const u16* ag = A  + (size_t)(rowBase+sr)*K + kb + sc;
        const u16* bg = Bt + (size_t)(colBase+sr)*K + kb + sc;
        uint4 av0 = *(const uint4*)ag;
        uint4 av1 = *(const uint4*)(ag+8);
        uint4 bv0 = *(const uint4*)bg;
        uint4 bv1 = *(const uint4*)(bg+8);
        *(uint4*)&As[sr*32 + sc]     = av0;
        *(uint4*)&As[sr*32 + sc + 8] = av1;
        *(uint4*)&Bs[sr*32 + sc]     = bv0;
        *(uint4*)&Bs[sr*32 + sc + 8] = bv1;
        __syncthreads();

        short8 af[4], bf[4];
        #pragma unroll
        for(int mt=0;mt<4;mt++)
            af[mt] = *(const short8*)&As[(wm*64+mt*16+ln15)*32 + quad*8];
        #pragma unroll
        for(int nt=0;nt<4;nt++)
            bf[nt] = *(const short8*)&Bs[(wn*64+nt*16+ln15)*32 + quad*8];
        #pragma unroll
        for(int mt=0;mt<4;mt++){
            #pragma unroll
            for(int nt=0;nt<4;nt++){
                acc[mt][nt] = __builtin_amdgcn_mfma_f32_16x16x32_bf16(
                                  af[mt], bf[nt], acc[mt][nt], 0, 0, 0);
            }
        }
        __syncthreads();
    }

    #pragma unroll
    for(int nt=0;nt<4;nt++){
        int n = colBase + wn*64 + nt*16 + ln15;
        float bv = bias[n];
        #pragma unroll
        for(int mt=0;mt<4;mt++){
            #pragma unroll
            for(int r=0;r<4;r++){
                int m = rowBase + wm*64 + mt*16 + quad*4 + r;
                float v = acc[mt][nt][r] + bv;
                if(RELU) v = fmaxf(v, 0.f);
                C[(size_t)m*N + n] = f2bf(v);
            }
        }
    }
}

// ---------------------------------------------------------------------------
// GRU scan: 256 blocks (one batch row) x 512 threads. Thread (p=tid>>8, j):
//   p=0: full Whr col j + Whn col j, k in [0,128)
//   p=1: full Whz col j + Whn col j, k in [128,256)
// = 192 weight VGPRs/thread held in SCALAR u32 arrays, each value passed
// through an empty asm volatile "+v" barrier: its SSA origin becomes the
// opaque asm, so LLVM CANNOT rematerialize the loads (the R4/R5/R7 failure
// mode). 192 pinned + ~40 working < 256-VGPR cap of launch_bounds(512,2)
// -> truly register-resident, no per-step weight traffic.
// ---------------------------------------------------------------------------
__global__ __launch_bounds__(512, 2)
void scan_kernel(const u16* __restrict__ gi, const void* __restrict__ dones,
                 const int* __restrict__ flags, const u32x4* __restrict__ Wt4,
                 const float* __restrict__ bhn, float* __restrict__ h_carry,
                 u16* __restrict__ y, int t0, int Tc)
{
    __shared__ __align__(16) u32 hbuf[2][128];   // 256 packed f16 each
    __shared__ float zpre[256];                  // iz + z_acc  (from p=1)
    __shared__ float n1b[256];                   // n-partial k>=128 (from p=1)
    const int tid = threadIdx.x;
    const int j   = tid & 255;
    const int p   = tid >> 8;
    const int row = blockIdx.x;
    const int fl  = flags[0];
    const int mode = (fl&1) ? 0 : ((fl&2) ? 2 : 1);  // 0=u8, 1=i32, 2=f32

    auto getdone = [&](int t)->bool{
        int idx = t*B_DIM + row;
        if(mode==0) return ((const unsigned char*)dones)[idx] != 0;
        if(mode==1) return ((const int*)dones)[idx] != 0;
        return ((const float*)dones)[idx] != 0.f;
    };

    // ---- one-time weight load into scalar regs, pinned via asm barrier ----
    const u32x4* baseA = Wt4 + (size_t)(p*32)*256 + j;          // m=0 or 1
    const u32x4* baseN = Wt4 + (size_t)(64 + p*16)*256 + j;     // m=2 halves
    u32 wAx[32], wAy[32], wAz[32], wAw[32];
    u32 wNx[16], wNy[16], wNz[16], wNw[16];
    #pragma unroll
    for(int q=0;q<32;q++){
        u32x4 t = baseA[q*256];
        wAx[q]=t[0]; wAy[q]=t[1]; wAz[q]=t[2]; wAw[q]=t[3];
    }
    #pragma unroll
    for(int q=0;q<16;q++){
        u32x4 t = baseN[q*256];
        wNx[q]=t[0]; wNy[q]=t[1]; wNz[q]=t[2]; wNw[q]=t[3];
    }
    #pragma unroll
    for(int q=0;q<32;q++)
        asm volatile("" : "+v"(wAx[q]), "+v"(wAy[q]), "+v"(wAz[q]), "+v"(wAw[q]));
    #pragma unroll
    for(int q=0;q<16;q++)
        asm volatile("" : "+v"(wNx[q]), "+v"(wNy[q]), "+v"(wNz[q]), "+v"(wNw[q]));

    const float bh = bhn[j];
    float hoj = 0.f;
    if(p == 0){
        bool d0 = getdone(t0);
        hoj = d0 ? 0.f : h_carry[(size_t)row*H_DIM + j];
        ((_Float16*)hbuf[0])[j] = (_Float16)hoj;
    }
    __syncthreads();

    int cur = 0;
    for(int t=0; t<Tc; ++t){
        // gate-input loads up front (latency hides under the dot phase)
        size_t gbase = ((size_t)t*B_DIM + row)*768;
        float gv0 = bf2f(gi[gbase + p*256 + j]);          // p=0: ir, p=1: iz
        float inn = 0.f; bool dn = false;
        if(p == 0){
            inn = bf2f(gi[gbase + 512 + j]);
            dn  = (t < Tc-1) ? getdone(t0+t+1) : false;
        }

        // dot: full matrix (r or z) over all k
        float a0=0.f, a1=0.f;
        const u32x4* hb  = (const u32x4*)hbuf[cur];
        const u32x4* hbN = hb + p*16;
        #pragma unroll
        for(int q=0;q<32;q++){
            u32x4 hv = hb[q];
            a0 = dot2(wAx[q], hv[0], a0);
            a1 = dot2(wAy[q], hv[1], a1);
            a0 = dot2(wAz[q], hv[2], a0);
            a1 = dot2(wAw[q], hv[3], a1);
        }
        // n half: p=0 uses h[k<128], p=1 uses h[k>=128]
        float n0=0.f, n1=0.f;
        #pragma unroll
        for(int q=0;q<16;q++){
            u32x4 hv = hbN[q];
            n0 = dot2(wNx[q], hv[0], n0);
            n1 = dot2(wNy[q], hv[1], n1);
            n0 = dot2(wNz[q], hv[2], n0);
            n1 = dot2(wNw[q], hv[3], n1);
        }
        if(p == 1){
            zpre[j] = gv0 + a0 + a1;   // iz + z_acc
            n1b[j]  = n0 + n1;
        }
        __syncthreads();

        if(p == 0){
            float r = 1.f/(1.f + __expf(-(gv0 + a0 + a1)));
            float z = 1.f/(1.f + __expf(-zpre[j]));
            float x = inn + r*(n0 + n1 + n1b[j] + bh);
            float e2 = __expf(2.f*x);
            float n = 1.f - 2.f/(e2 + 1.f);          // tanh(x)
            float hn = (1.f - z)*n + z*hoj;
            y[((size_t)t*B_DIM + row)*H_DIM + j] = f2bf(hn);
            hoj = dn ? 0.f : hn;                     // dn=false on last chunk step
            ((_Float16*)hbuf[cur^1])[j] = (_Float16)hoj;
        }
        __syncthreads();
        cur ^= 1;
    }

    if(p == 0) h_carry[(size_t)row*H_DIM + j] = hoj;  // raw carry
}

// ---------------------------------------------------------------------------
// Actor head stage 2: logits[rows,32] = ah[rows,256] @ W_a2 + b_a2 - (1-avail)*1e10
// ---------------------------------------------------------------------------
__global__ __launch_bounds__(256)
void actor2_kernel(const u16* __restrict__ ah, const float* __restrict__ W_a2,
                   const float* __restrict__ b_a2, const float* __restrict__ avail,
                   float* __restrict__ logits)
{
    __shared__ u16 ahs[64][264];
    const int tid = threadIdx.x;
    const int r0 = blockIdx.x*64;
    {
        int row = tid & 63;
        int c0 = (tid >> 6) * 64;
        const uint4* gp = (const uint4*)(ah + (size_t)(r0+row)*H_DIM + c0);
        #pragma unroll
        for(int q=0;q<8;q++){
            uint4 u = gp[q];
            u32* dst = (u32*)&ahs[row][c0 + q*8];
            dst[0]=u.x; dst[1]=u.y; dst[2]=u.z; dst[3]=u.w;
        }
    }
    __syncthreads();
    const int c  = tid & 31;
    const int rg = tid >> 5;   // 0..7
    float acc[8]={0.f,0.f,0.f,0.f,0.f,0.f,0.f,0.f};
    float bc = b_a2[c];
    for(int k=0;k<H_DIM;k+=4){
        float w0 = W_a2[(k+0)*A_DIM + c];
        float w1 = W_a2[(k+1)*A_DIM + c];
        float w2 = W_a2[(k+2)*A_DIM + c];
        float w3 = W_a2[(k+3)*A_DIM + c];
        #pragma unroll
        for(int rr=0;rr<8;rr++){
            uint2 av = *(const uint2*)&ahs[rg*8+rr][k];
            float2 p0 = bfpair(av.x), p1 = bfpair(av.y);
            acc[rr] = fmaf(p0.x,w0,fmaf(p0.y,w1,fmaf(p1.x,w2,fmaf(p1.y,w3,acc[rr]))));
        }
    }
    #pragma unroll
    for(int rr=0;rr<8;rr++){
        int grow = r0 + rg*8 + rr;
        float av = avail[(size_t)grow*A_DIM + c];
        logits[(size_t)grow*A_DIM + c] = acc[rr] + bc - (1.f-av)*1e10f;
    }
}

// ---------------------------------------------------------------------------
// Critic head stage 2: value[row] = ch[row,256] @ W_c2 + b_c2. Wave per row.
// ---------------------------------------------------------------------------
__global__ __launch_bounds__(256)
void critic2_kernel(const u16* __restrict__ ch, const float* __restrict__ W_c2,
                    const float* __restrict__ b_c2, float* __restrict__ value)
{
    const int lane = threadIdx.x & 63;
    const int wid  = threadIdx.x >> 6;
    const int row  = blockIdx.x*4 + wid;
    uint2 av = *(const uint2*)(ch + (size_t)row*H_DIM + lane*4);
    float2 p0 = bfpair(av.x), p1 = bfpair(av.y);
    float4 wv = *(const float4*)(W_c2 + lane*4);
    float acc = p0.x*wv.x + p0.y*wv.y + p1.x*wv.z + p1.y*wv.w;
    #pragma unroll
    for(int off=32; off>0; off>>=1) acc += __shfl_down(acc, off, 64);
    if(lane==0) value[row] = acc + b_c2[0];
}

// ---------------------------------------------------------------------------
extern "C" void kernel_launch(void* const* d_in, const int* in_sizes, int n_in,
                              void* d_out, int out_size, void* d_ws, size_t ws_size,
                              hipStream_t stream)
{
    const float* hidden = (const float*)d_in[0];
    const float* obs    = (const float*)d_in[1];
    const void*  dones  = d_in[2];
    const float* avail  = (const float*)d_in[3];
    const float* W_emb  = (const float*)d_in[4];
    const float* b_emb  = (const float*)d_in[5];
    const float* Wi     = (const float*)d_in[6];
    const float* bi     = (const float*)d_in[7];
    const float* Whr    = (const float*)d_in[8];
    const float* Whz    = (const float*)d_in[9];
    const float* Whn    = (const float*)d_in[10];
    const float* bhn    = (const float*)d_in[11];
    const float* W_a1   = (const float*)d_in[12];
    const float* b_a1   = (const float*)d_in[13];
    const float* W_a2   = (const float*)d_in[14];
    const float* b_a2   = (const float*)d_in[15];
    const float* W_c1   = (const float*)d_in[16];
    const float* b_c1   = (const float*)d_in[17];
    const float* W_c2   = (const float*)d_in[18];
    const float* b_c2   = (const float*)d_in[19];

    float* out_hidden = (float*)d_out;                       // 65536
    float* out_logits = out_hidden + (size_t)B_DIM*H_DIM;    // 4194304
    float* out_value  = out_logits + (size_t)TB*A_DIM;       // 131072

    // ---- workspace layout (chunk size adapted to ws_size, deterministic) ----
    const size_t fixed = 393216 + 393216 + 131072 + 131072 + 262144 + 256;
    int Tc = 4;
    for(int cand = 64; cand >= 4; cand >>= 1){
        size_t need = fixed + (size_t)cand*(393216 /*gi*/ + 2*131072 /*emb, y*/);
        if(need <= ws_size){ Tc = cand; break; }
    }
    const int NC = T_DIM / Tc;

    uint8_t* ws = (uint8_t*)d_ws;
    size_t off = 0;
    u32*  wt_b    = (u32*)(ws + off); off += 393216;   // scan weights, packed f16
    u16*  wiT     = (u16*)(ws + off); off += 393216;   // Wi^T bf16 [768][256]
    u16*  wa1T    = (u16*)(ws + off); off += 131072;   // W_a1^T bf16 [256][256]
    u16*  wc1T    = (u16*)(ws + off); off += 131072;   // W_c1^T bf16 [256][256]
    float* h_carry= (float*)(ws + off); off += 262144;
    int*  flags   = (int*)(ws + off); off += 256;
    u16*  gi_c    = (u16*)(ws + off); off += (size_t)Tc*393216;
    u16*  emb_c   = (u16*)(ws + off); off += (size_t)Tc*131072;  // also ah_c, ch_c
    u16*  y_c     = (u16*)(ws + off); off += (size_t)Tc*131072;
    u16*  ah_c    = emb_c;
    u16*  ch_c    = emb_c;

    zero_flags_kernel<<<1, 64, 0, stream>>>(flags);
    detect_kernel<<<64, 256, 0, stream>>>((const unsigned char*)dones, TB, flags);
    cvt_wt_kernel<<<384, 256, 0, stream>>>(Whr, Whz, Whn, wt_b);
    cvt_wT_kernel<<<768, 256, 0, stream>>>(Wi,   wiT,  256, 768);
    cvt_wT_kernel<<<256, 256, 0, stream>>>(W_a1, wa1T, 256, 256);
    cvt_wT_kernel<<<256, 256, 0, stream>>>(W_c1, wc1T, 256, 256);
    hipMemcpyAsync(h_carry, hidden, (size_t)B_DIM*H_DIM*sizeof(float),
                   hipMemcpyDeviceToDevice, stream);

    const int Mc = Tc*B_DIM;
    const int gy = Mc/128;

    for(int c = 0; c < NC; ++c){
        const int t0 = c*Tc;
        const float* obs_c = obs + (size_t)t0*B_DIM*OBS_DIM;
        // emb = relu(obs @ W_emb + b_emb)  (f32 A)
        gemm_f32_kernel<<<dim3(2,gy), 256, 0, stream>>>(obs_c, W_emb, b_emb, emb_c, Mc, 256, 128);
        // gi = emb @ Wi + bi  (MFMA)
        gemm_mfma_kernel<0><<<dim3(6,gy), 256, 0, stream>>>(emb_c, wiT, bi, gi_c, Mc, 768, 256);
        // GRU scan chunk: 256 blocks (one per batch row) x 512 threads
        scan_kernel<<<256, 512, 0, stream>>>(gi_c, dones, flags, (const u32x4*)wt_b,
                                             bhn, h_carry, y_c, t0, Tc);
        // actor head
        gemm_mfma_kernel<1><<<dim3(2,gy), 256, 0, stream>>>(y_c, wa1T, b_a1, ah_c, Mc, 256, 256);
        actor2_kernel<<<Mc/64, 256, 0, stream>>>(ah_c, W_a2, b_a2,
                                                 avail + (size_t)t0*B_DIM*A_DIM,
                                                 out_logits + (size_t)t0*B_DIM*A_DIM);
        // critic head
        gemm_mfma_kernel<1><<<dim3(2,gy), 256, 0, stream>>>(y_c, wc1T, b_c1, ch_c, Mc, 256, 256);
        critic2_kernel<<<Mc/4, 256, 0, stream>>>(ch_c, W_c2, b_c2, out_value + (size_t)t0*B_DIM);
    }

    hipMemcpyAsync(out_hidden, h_carry, (size_t)B_DIM*H_DIM*sizeof(float),
                   hipMemcpyDeviceToDevice, stream);
}

// Round 9
// 1516.510 us; speedup vs baseline: 2.2267x; 1.1486x over previous
//
#include <hip/hip_runtime.h>
#include <stdint.h>

#define T_DIM 512
#define B_DIM 256
#define OBS_DIM 128
#define H_DIM 256
#define A_DIM 32
#define TB (T_DIM*B_DIM)   // 131072

typedef unsigned short u16;
typedef unsigned int   u32;
typedef _Float16 half2v __attribute__((ext_vector_type(2)));
typedef __attribute__((ext_vector_type(8))) short short8;   // 8 bf16 (4 VGPRs)
typedef __attribute__((ext_vector_type(4))) float f32x4;
typedef __attribute__((ext_vector_type(4))) u32   u32x4;

__device__ __forceinline__ float bf2f(u16 v){ return __uint_as_float(((u32)v)<<16); }
__device__ __forceinline__ u16 f2bf(float f){
    u32 x = __float_as_uint(f);
    u32 r = x + 0x7fffu + ((x>>16)&1u);   // round-to-nearest-even
    return (u16)(r>>16);
}
__device__ __forceinline__ float2 bfpair(u32 u){
    return make_float2(__uint_as_float(u<<16), __uint_as_float(u & 0xffff0000u));
}

// packed-f16-pair dot: acc += a.lo*b.lo + a.hi*b.hi
__device__ __forceinline__ float dot2(u32 a, u32 b, float c){
#if __has_builtin(__builtin_amdgcn_fdot2)
    return __builtin_amdgcn_fdot2(__builtin_bit_cast(half2v,a),
                                  __builtin_bit_cast(half2v,b), c, false);
#else
    half2v ha = __builtin_bit_cast(half2v,a), hb = __builtin_bit_cast(half2v,b);
    return fmaf((float)ha[0],(float)hb[0], fmaf((float)ha[1],(float)hb[1], c));
#endif
}

// ---------------------------------------------------------------------------
// dones dtype probe (u8 bool vs i32 vs f32) via nonzero byte positions mod 4.
// ---------------------------------------------------------------------------
__global__ void zero_flags_kernel(int* p){ if(threadIdx.x<4) p[threadIdx.x]=0; }

__global__ void detect_kernel(const unsigned char* __restrict__ d, int n, int* __restrict__ flags){
    int f=0;
    for(int p = blockIdx.x*blockDim.x+threadIdx.x; p<n; p += gridDim.x*blockDim.x){
        if(d[p]){ int m=p&3; if(m==1) f|=1; else if(m>=2) f|=2; }
    }
    if(f) atomicOr(flags, f);
}

// ---------------------------------------------------------------------------
// Recurrent weights -> packed f16 pairs: dst[((m*32+q)*256 + j)*4 + e] packs
// k=2*(4q+e), 2*(4q+e)+1 of column j of matrix m (q covers k=8q..8q+7).
// ---------------------------------------------------------------------------
__global__ void cvt_wt_kernel(const float* __restrict__ Whr, const float* __restrict__ Whz,
                              const float* __restrict__ Whn, u32* __restrict__ dst){
    int i = blockIdx.x*blockDim.x + threadIdx.x;
    if(i >= 3*32*256*4) return;
    int e = i & 3;
    int j = (i >> 2) & 255;
    int q = (i >> 10) & 31;
    int m = i >> 15;
    const float* W = (m==0) ? Whr : (m==1) ? Whz : Whn;
    int kp = q*4 + e, k = 2*kp;
    _Float16 lo = (_Float16)W[(size_t)k    *H_DIM + j];
    _Float16 hi = (_Float16)W[(size_t)(k+1)*H_DIM + j];
    dst[i] = (u32)__builtin_bit_cast(u16,lo) | ((u32)__builtin_bit_cast(u16,hi) << 16);
}

// GEMM weight f32 [K][N] -> bf16 transposed [N][K]
__global__ void cvt_wT_kernel(const float* __restrict__ W, u16* __restrict__ dst,
                              int K, int N){
    int i = blockIdx.x*blockDim.x + threadIdx.x;
    if(i >= K*N) return;
    int n = i / K;
    int k = i - n*K;
    dst[i] = f2bf(W[(size_t)k*N + n]);
}

// ---------------------------------------------------------------------------
// MFMA bf16 GEMM: C[M,N](bf16) = opt_relu(A @ Bt^T + bias), Bt bf16 [N][K].
// A is bf16 (AF32=0) or f32 converted during staging (AF32=1).
// 128x128 tile, BK=32, 4 waves 2x2, 16x mfma_f32_16x16x32_bf16 each.
// ---------------------------------------------------------------------------
template<int RELU, int AF32>
__global__ __launch_bounds__(256, 2)
void gemm_mfma_kernel(const void* __restrict__ A_, const u16* __restrict__ Bt,
                      const float* __restrict__ bias, u16* __restrict__ C,
                      int M, int N, int K)
{
    __shared__ u16 As[128*32];
    __shared__ u16 Bs[128*32];
    const int tid  = threadIdx.x;
    const int wave = tid >> 6;
    const int lane = tid & 63;
    const int ln15 = lane & 15;
    const int quad = lane >> 4;
    const int wm = wave & 1, wn = wave >> 1;
    const int rowBase = blockIdx.y*128;
    const int colBase = blockIdx.x*128;

    f32x4 acc[4][4] = {};

    const int sr = tid >> 1;
    const int sc = (tid & 1) * 16;

    for(int kb = 0; kb < K; kb += 32){
        if(AF32){
            const float* af = (const float*)A_;
            const float* ag = af + (size_t)(rowBase+sr)*K + kb + sc;
            float4 f0 = *(const float4*)ag;
            float4 f1 = *(const float4*)(ag+4);
            float4 f2 = *(const float4*)(ag+8);
            float4 f3 = *(const float4*)(ag+12);
            u16 tmp[16] = { f2bf(f0.x),f2bf(f0.y),f2bf(f0.z),f2bf(f0.w),
                            f2bf(f1.x),f2bf(f1.y),f2bf(f1.z),f2bf(f1.w),
                            f2bf(f2.x),f2bf(f2.y),f2bf(f2.z),f2bf(f2.w),
                            f2bf(f3.x),f2bf(f3.y),f2bf(f3.z),f2bf(f3.w) };
            *(uint4*)&As[sr*32 + sc]     = *(const uint4*)&tmp[0];
            *(uint4*)&As[sr*32 + sc + 8] = *(const uint4*)&tmp[8];
        } else {
            const u16* ab = (const u16*)A_;
            const u16* ag = ab + (size_t)(rowBase+sr)*K + kb + sc;
            uint4 av0 = *(const uint4*)ag;
            uint4 av1 = *(const uint4*)(ag+8);
            *(uint4*)&As[sr*32 + sc]     = av0;
            *(uint4*)&As[sr*32 + sc + 8] = av1;
        }
        {
            const u16* bg = Bt + (size_t)(colBase+sr)*K + kb + sc;
            uint4 bv0 = *(const uint4*)bg;
            uint4 bv1 = *(const uint4*)(bg+8);
            *(uint4*)&Bs[sr*32 + sc]     = bv0;
            *(uint4*)&Bs[sr*32 + sc + 8] = bv1;
        }
        __syncthreads();

        short8 af[4], bf[4];
        #pragma unroll
        for(int mt=0;mt<4;mt++)
            af[mt] = *(const short8*)&As[(wm*64+mt*16+ln15)*32 + quad*8];
        #pragma unroll
        for(int nt=0;nt<4;nt++)
            bf[nt] = *(const short8*)&Bs[(wn*64+nt*16+ln15)*32 + quad*8];
        #pragma unroll
        for(int mt=0;mt<4;mt++){
            #pragma unroll
            for(int nt=0;nt<4;nt++){
                acc[mt][nt] = __builtin_amdgcn_mfma_f32_16x16x32_bf16(
                                  af[mt], bf[nt], acc[mt][nt], 0, 0, 0);
            }
        }
        __syncthreads();
    }

    #pragma unroll
    for(int nt=0;nt<4;nt++){
        int n = colBase + wn*64 + nt*16 + ln15;
        float bv = bias[n];
        #pragma unroll
        for(int mt=0;mt<4;mt++){
            #pragma unroll
            for(int r=0;r<4;r++){
                int m = rowBase + wm*64 + mt*16 + quad*4 + r;
                float v = acc[mt][nt][r] + bv;
                if(RELU) v = fmaxf(v, 0.f);
                C[(size_t)m*N + n] = f2bf(v);
            }
        }
    }
}

// ---------------------------------------------------------------------------
// GRU scan: 256 blocks (one batch row) x 512 threads. Thread (p=tid>>8, j)
// owns the k-half [128p, 128p+128) of ALL THREE matrix columns j:
// 3 x 16 u32x4 = 192 weight VGPRs, pinned via empty asm "+v" (no remat).
// NO min-waves in launch_bounds: the (512,2) of R8 capped arch VGPRs at 128
// and forced AGPR spills -- that was the 1.9us/step. Per-step LDS h-reads
// drop 48->16 ds_read_b128/thread (hv reused across r/z/n).
// p=1 ships its 3 high-half partials through LDS; p=0 computes gates.
// ---------------------------------------------------------------------------
__global__ __launch_bounds__(512)
void scan_kernel(const u16* __restrict__ gi, const void* __restrict__ dones,
                 const int* __restrict__ flags, const u32x4* __restrict__ Wt4,
                 const float* __restrict__ bhn, float* __restrict__ h_carry,
                 u16* __restrict__ y, int t0, int Tc)
{
    __shared__ __align__(16) u32 hbuf[2][128];   // 256 packed f16 each
    __shared__ float rex[3][256];                // r-hi, (iz + z-hi), n-hi
    const int tid = threadIdx.x;
    const int j   = tid & 255;
    const int p   = tid >> 8;
    const int row = blockIdx.x;
    const int fl  = flags[0];
    const int mode = (fl&1) ? 0 : ((fl&2) ? 2 : 1);  // 0=u8, 1=i32, 2=f32

    auto getdone = [&](int t)->bool{
        int idx = t*B_DIM + row;
        if(mode==0) return ((const unsigned char*)dones)[idx] != 0;
        if(mode==1) return ((const int*)dones)[idx] != 0;
        return ((const float*)dones)[idx] != 0.f;
    };

    // ---- one-time weight load: k-half p of columns j of Whr/Whz/Whn ----
    const u32x4* baseR = Wt4 + (size_t)( 0 + p*16)*256 + j;
    const u32x4* baseZ = Wt4 + (size_t)(32 + p*16)*256 + j;
    const u32x4* baseN = Wt4 + (size_t)(64 + p*16)*256 + j;
    u32 wRx[16],wRy[16],wRz[16],wRw[16];
    u32 wZx[16],wZy[16],wZz[16],wZw[16];
    u32 wNx[16],wNy[16],wNz[16],wNw[16];
    #pragma unroll
    for(int q=0;q<16;q++){
        u32x4 tr = baseR[q*256]; wRx[q]=tr[0]; wRy[q]=tr[1]; wRz[q]=tr[2]; wRw[q]=tr[3];
        u32x4 tz = baseZ[q*256]; wZx[q]=tz[0]; wZy[q]=tz[1]; wZz[q]=tz[2]; wZw[q]=tz[3];
        u32x4 tn = baseN[q*256]; wNx[q]=tn[0]; wNy[q]=tn[1]; wNz[q]=tn[2]; wNw[q]=tn[3];
    }
    #pragma unroll
    for(int q=0;q<16;q++){
        asm volatile("" : "+v"(wRx[q]), "+v"(wRy[q]), "+v"(wRz[q]), "+v"(wRw[q]),
                          "+v"(wZx[q]), "+v"(wZy[q]), "+v"(wZz[q]), "+v"(wZw[q]),
                          "+v"(wNx[q]), "+v"(wNy[q]), "+v"(wNz[q]), "+v"(wNw[q]));
    }

    const float bh = bhn[j];
    float hoj = 0.f;
    if(p == 0){
        bool d0 = getdone(t0);
        hoj = d0 ? 0.f : h_carry[(size_t)row*H_DIM + j];
        ((_Float16*)hbuf[0])[j] = (_Float16)hoj;
    }
    __syncthreads();

    int cur = 0;
    for(int t=0; t<Tc; ++t){
        // gate-input loads up front (latency hides under the dot phase)
        size_t gbase = ((size_t)t*B_DIM + row)*768;
        float ir=0.f, inn=0.f, izv=0.f; bool dn=false;
        if(p == 0){
            ir  = bf2f(gi[gbase + j]);
            inn = bf2f(gi[gbase + 512 + j]);
            dn  = (t < Tc-1) ? getdone(t0+t+1) : false;
        } else {
            izv = bf2f(gi[gbase + 256 + j]);
        }

        // dots over this thread's k-half for all three matrices
        float r0=0.f,r1=0.f,z0=0.f,z1=0.f,n0=0.f,n1=0.f;
        const u32x4* hb = (const u32x4*)hbuf[cur] + p*16;
        #pragma unroll
        for(int q=0;q<16;q++){
            u32x4 hv = hb[q];
            r0 = dot2(wRx[q], hv[0], r0); r1 = dot2(wRy[q], hv[1], r1);
            r0 = dot2(wRz[q], hv[2], r0); r1 = dot2(wRw[q], hv[3], r1);
            z0 = dot2(wZx[q], hv[0], z0); z1 = dot2(wZy[q], hv[1], z1);
            z0 = dot2(wZz[q], hv[2], z0); z1 = dot2(wZw[q], hv[3], z1);
            n0 = dot2(wNx[q], hv[0], n0); n1 = dot2(wNy[q], hv[1], n1);
            n0 = dot2(wNz[q], hv[2], n0); n1 = dot2(wNw[q], hv[3], n1);
        }
        if(p == 1){
            rex[0][j] = r0 + r1;
            rex[1][j] = izv + z0 + z1;
            rex[2][j] = n0 + n1;
        }
        __syncthreads();

        if(p == 0){
            float r = 1.f/(1.f + __expf(-(ir + r0 + r1 + rex[0][j])));
            float z = 1.f/(1.f + __expf(-(z0 + z1 + rex[1][j])));
            float x = inn + r*(n0 + n1 + rex[2][j] + bh);
            float e2 = __expf(2.f*x);
            float n = 1.f - 2.f/(e2 + 1.f);          // tanh(x)
            float hn = (1.f - z)*n + z*hoj;
            y[((size_t)t*B_DIM + row)*H_DIM + j] = f2bf(hn);
            hoj = dn ? 0.f : hn;                     // dn=false on last chunk step
            ((_Float16*)hbuf[cur^1])[j] = (_Float16)hoj;
        }
        __syncthreads();
        cur ^= 1;
    }

    if(p == 0) h_carry[(size_t)row*H_DIM + j] = hoj;  // raw carry
}

// ---------------------------------------------------------------------------
// Actor head stage 2: logits[rows,32] = ah[rows,256] @ W_a2 + b_a2 - (1-avail)*1e10
// ---------------------------------------------------------------------------
__global__ __launch_bounds__(256)
void actor2_kernel(const u16* __restrict__ ah, const float* __restrict__ W_a2,
                   const float* __restrict__ b_a2, const float* __restrict__ avail,
                   float* __restrict__ logits)
{
    __shared__ u16 ahs[64][264];
    const int tid = threadIdx.x;
    const int r0 = blockIdx.x*64;
    {
        int row = tid & 63;
        int c0 = (tid >> 6) * 64;
        const uint4* gp = (const uint4*)(ah + (size_t)(r0+row)*H_DIM + c0);
        #pragma unroll
        for(int q=0;q<8;q++){
            uint4 u = gp[q];
            u32* dst = (u32*)&ahs[row][c0 + q*8];
            dst[0]=u.x; dst[1]=u.y; dst[2]=u.z; dst[3]=u.w;
        }
    }
    __syncthreads();
    const int c  = tid & 31;
    const int rg = tid >> 5;   // 0..7
    float acc[8]={0.f,0.f,0.f,0.f,0.f,0.f,0.f,0.f};
    float bc = b_a2[c];
    for(int k=0;k<H_DIM;k+=4){
        float w0 = W_a2[(k+0)*A_DIM + c];
        float w1 = W_a2[(k+1)*A_DIM + c];
        float w2 = W_a2[(k+2)*A_DIM + c];
        float w3 = W_a2[(k+3)*A_DIM + c];
        #pragma unroll
        for(int rr=0;rr<8;rr++){
            uint2 av = *(const uint2*)&ahs[rg*8+rr][k];
            float2 p0 = bfpair(av.x), p1 = bfpair(av.y);
            acc[rr] = fmaf(p0.x,w0,fmaf(p0.y,w1,fmaf(p1.x,w2,fmaf(p1.y,w3,acc[rr]))));
        }
    }
    #pragma unroll
    for(int rr=0;rr<8;rr++){
        int grow = r0 + rg*8 + rr;
        float av = avail[(size_t)grow*A_DIM + c];
        logits[(size_t)grow*A_DIM + c] = acc[rr] + bc - (1.f-av)*1e10f;
    }
}

// ---------------------------------------------------------------------------
// Critic head stage 2: value[row] = ch[row,256] @ W_c2 + b_c2. Wave per row.
// ---------------------------------------------------------------------------
__global__ __launch_bounds__(256)
void critic2_kernel(const u16* __restrict__ ch, const float* __restrict__ W_c2,
                    const float* __restrict__ b_c2, float* __restrict__ value)
{
    const int lane = threadIdx.x & 63;
    const int wid  = threadIdx.x >> 6;
    const int row  = blockIdx.x*4 + wid;
    uint2 av = *(const uint2*)(ch + (size_t)row*H_DIM + lane*4);
    float2 p0 = bfpair(av.x), p1 = bfpair(av.y);
    float4 wv = *(const float4*)(W_c2 + lane*4);
    float acc = p0.x*wv.x + p0.y*wv.y + p1.x*wv.z + p1.y*wv.w;
    #pragma unroll
    for(int off=32; off>0; off>>=1) acc += __shfl_down(acc, off, 64);
    if(lane==0) value[row] = acc + b_c2[0];
}

// ---------------------------------------------------------------------------
extern "C" void kernel_launch(void* const* d_in, const int* in_sizes, int n_in,
                              void* d_out, int out_size, void* d_ws, size_t ws_size,
                              hipStream_t stream)
{
    const float* hidden = (const float*)d_in[0];
    const float* obs    = (const float*)d_in[1];
    const void*  dones  = d_in[2];
    const float* avail  = (const float*)d_in[3];
    const float* W_emb  = (const float*)d_in[4];
    const float* b_emb  = (const float*)d_in[5];
    const float* Wi     = (const float*)d_in[6];
    const float* bi     = (const float*)d_in[7];
    const float* Whr    = (const float*)d_in[8];
    const float* Whz    = (const float*)d_in[9];
    const float* Whn    = (const float*)d_in[10];
    const float* bhn    = (const float*)d_in[11];
    const float* W_a1   = (const float*)d_in[12];
    const float* b_a1   = (const float*)d_in[13];
    const float* W_a2   = (const float*)d_in[14];
    const float* b_a2   = (const float*)d_in[15];
    const float* W_c1   = (const float*)d_in[16];
    const float* b_c1   = (const float*)d_in[17];
    const float* W_c2   = (const float*)d_in[18];
    const float* b_c2   = (const float*)d_in[19];

    float* out_hidden = (float*)d_out;                       // 65536
    float* out_logits = out_hidden + (size_t)B_DIM*H_DIM;    // 4194304
    float* out_value  = out_logits + (size_t)TB*A_DIM;       // 131072

    // ---- workspace layout (chunk size adapted to ws_size, deterministic) ----
    const size_t fixed = 393216 + 393216 + 131072 + 131072 + 65536 + 262144 + 256;
    int Tc = 4;
    for(int cand = 64; cand >= 4; cand >>= 1){
        size_t need = fixed + (size_t)cand*(393216 /*gi*/ + 2*131072 /*emb, y*/);
        if(need <= ws_size){ Tc = cand; break; }
    }
    const int NC = T_DIM / Tc;

    uint8_t* ws = (uint8_t*)d_ws;
    size_t off = 0;
    u32*  wt_b    = (u32*)(ws + off); off += 393216;   // scan weights, packed f16
    u16*  wiT     = (u16*)(ws + off); off += 393216;   // Wi^T bf16 [768][256]
    u16*  wa1T    = (u16*)(ws + off); off += 131072;   // W_a1^T bf16 [256][256]
    u16*  wc1T    = (u16*)(ws + off); off += 131072;   // W_c1^T bf16 [256][256]
    u16*  wembT   = (u16*)(ws + off); off += 65536;    // W_emb^T bf16 [256][128]
    float* h_carry= (float*)(ws + off); off += 262144;
    int*  flags   = (int*)(ws + off); off += 256;
    u16*  gi_c    = (u16*)(ws + off); off += (size_t)Tc*393216;
    u16*  emb_c   = (u16*)(ws + off); off += (size_t)Tc*131072;  // also ah_c, ch_c
    u16*  y_c     = (u16*)(ws + off); off += (size_t)Tc*131072;
    u16*  ah_c    = emb_c;
    u16*  ch_c    = emb_c;

    zero_flags_kernel<<<1, 64, 0, stream>>>(flags);
    detect_kernel<<<64, 256, 0, stream>>>((const unsigned char*)dones, TB, flags);
    cvt_wt_kernel<<<384, 256, 0, stream>>>(Whr, Whz, Whn, wt_b);
    cvt_wT_kernel<<<768, 256, 0, stream>>>(Wi,   wiT,  256, 768);
    cvt_wT_kernel<<<256, 256, 0, stream>>>(W_a1, wa1T, 256, 256);
    cvt_wT_kernel<<<256, 256, 0, stream>>>(W_c1, wc1T, 256, 256);
    cvt_wT_kernel<<<128, 256, 0, stream>>>(W_emb, wembT, 128, 256);
    hipMemcpyAsync(h_carry, hidden, (size_t)B_DIM*H_DIM*sizeof(float),
                   hipMemcpyDeviceToDevice, stream);

    const int Mc = Tc*B_DIM;
    const int gy = Mc/128;

    for(int c = 0; c < NC; ++c){
        const int t0 = c*Tc;
        const float* obs_c = obs + (size_t)t0*B_DIM*OBS_DIM;
        // emb = relu(obs @ W_emb + b_emb)  (MFMA, f32 A converted in staging)
        gemm_mfma_kernel<1,1><<<dim3(2,gy), 256, 0, stream>>>(obs_c, wembT, b_emb, emb_c, Mc, 256, 128);
        // gi = emb @ Wi + bi  (MFMA)
        gemm_mfma_kernel<0,0><<<dim3(6,gy), 256, 0, stream>>>(emb_c, wiT, bi, gi_c, Mc, 768, 256);
        // GRU scan chunk: 256 blocks (one per batch row) x 512 threads
        scan_kernel<<<256, 512, 0, stream>>>(gi_c, dones, flags, (const u32x4*)wt_b,
                                             bhn, h_carry, y_c, t0, Tc);
        // actor head
        gemm_mfma_kernel<1,0><<<dim3(2,gy), 256, 0, stream>>>(y_c, wa1T, b_a1, ah_c, Mc, 256, 256);
        actor2_kernel<<<Mc/64, 256, 0, stream>>>(ah_c, W_a2, b_a2,
                                                 avail + (size_t)t0*B_DIM*A_DIM,
                                                 out_logits + (size_t)t0*B_DIM*A_DIM);
        // critic head
        gemm_mfma_kernel<1,0><<<dim3(2,gy), 256, 0, stream>>>(y_c, wc1T, b_c1, ch_c, Mc, 256, 256);
        critic2_kernel<<<Mc/4, 256, 0, stream>>>(ch_c, W_c2, b_c2, out_value + (size_t)t0*B_DIM);
    }

    hipMemcpyAsync(out_hidden, h_carry, (size_t)B_DIM*H_DIM*sizeof(float),
                   hipMemcpyDeviceToDevice, stream);
}